// Round 1
// baseline (1159.940 us; speedup 1.0000x reference)
//
#include <hip/hip_runtime.h>
#include <math.h>

// AttentionContextEncoder fused kernel, fp32, wave-per-4-rows, no barriers.
// B=131072, E=64, H=4, D=16, tokens S=5. Out: (B,160) fp32.

#define NROWS 131072
#define M 4        // rows per wave
#define WAVES 4    // waves per block (block = 256 threads)

template<int IN, int HID>
__device__ __forceinline__ void branch_block(
    const float* __restrict__ Wp, const float* __restrict__ bp,
    const float* __restrict__ Wu, const float* __restrict__ bu,
    float* __restrict__ A, float* __restrict__ X, int lane, int in_off, int s)
{
  // hidden = relu(in @ Wp + bp), in staged at A[m*100+in_off+i], hid -> A[400+m*64+j]
  if (lane < HID) {
    float hh[M];
    #pragma unroll
    for (int m = 0; m < M; ++m) hh[m] = bp[lane];
    #pragma unroll
    for (int i = 0; i < IN; ++i) {
      float w = Wp[i * HID + lane];
      #pragma unroll
      for (int m = 0; m < M; ++m) hh[m] += A[m * 100 + in_off + i] * w;
    }
    #pragma unroll
    for (int m = 0; m < M; ++m) A[400 + m * 64 + lane] = fmaxf(hh[m], 0.0f);
  }
  // x_s = hid @ Wu + bu (linear), all 64 lanes, lane = e
  float xs[M];
  #pragma unroll
  for (int m = 0; m < M; ++m) xs[m] = bu[lane];
  #pragma unroll
  for (int j = 0; j < HID; ++j) {
    float w = Wu[j * 64 + lane];
    #pragma unroll
    for (int m = 0; m < M; ++m) xs[m] += A[400 + m * 64 + j] * w;
  }
  #pragma unroll
  for (int m = 0; m < M; ++m) X[m * 320 + s * 64 + lane] = xs[m];
}

__global__ __launch_bounds__(256, 2) void ace_fused(
    const float* __restrict__ visual, const float* __restrict__ audio,
    const float* __restrict__ pose,   const float* __restrict__ spatial,
    const float* __restrict__ timex,
    const float* __restrict__ Wv_p, const float* __restrict__ bv_p,
    const float* __restrict__ Wa_p, const float* __restrict__ ba_p,
    const float* __restrict__ Wp_p, const float* __restrict__ bp_p,
    const float* __restrict__ Ws_p, const float* __restrict__ bs_p,
    const float* __restrict__ Wt_p, const float* __restrict__ bt_p,
    const float* __restrict__ Wv_u, const float* __restrict__ bv_u,
    const float* __restrict__ Wa_u, const float* __restrict__ ba_u,
    const float* __restrict__ Wp_u, const float* __restrict__ bp_u,
    const float* __restrict__ Ws_u, const float* __restrict__ bs_u,
    const float* __restrict__ Wt_u, const float* __restrict__ bt_u,
    const float* __restrict__ Wq,  const float* __restrict__ bq,
    const float* __restrict__ Wk,  const float* __restrict__ bk,
    const float* __restrict__ Wvv, const float* __restrict__ bvv,
    const float* __restrict__ Wo,  const float* __restrict__ bo,
    const float* __restrict__ gamma, const float* __restrict__ beta,
    const float* __restrict__ W1, const float* __restrict__ b1,
    const float* __restrict__ W2, const float* __restrict__ b2,
    float* __restrict__ out)
{
  __shared__ float lds[WAVES][2560];
  const int tid  = threadIdx.x;
  const int wave = tid >> 6;
  const int lane = tid & 63;
  float* X = lds[wave];      // 1280 floats: x[m][s][e] then flat (in place)
  float* A = X + 1280;       // 1280 floats: union {in[m][100] + hid[m][64]} -> o[m][320] -> fused[m][256]
  const int rowBase = (blockIdx.x * WAVES + wave) * M;

  // ---------------- phase 1: stage raw inputs ----------------
  #pragma unroll
  for (int m = 0; m < M; ++m) {
    const int r = rowBase + m;
    if (lane < 14) A[m * 100 +  0 + lane] = visual [r * 14 + lane];
    if (lane < 17) A[m * 100 + 14 + lane] = audio  [r * 17 + lane];
    if (lane < 51) A[m * 100 + 31 + lane] = pose   [r * 51 + lane];
    if (lane <  7) A[m * 100 + 82 + lane] = spatial[r *  7 + lane];
    if (lane < 10) A[m * 100 + 89 + lane] = timex  [r * 10 + lane];
  }

  // ---------------- phase 2: five modality branches ----------------
  branch_block<14, 32>(Wv_p, bv_p, Wv_u, bv_u, A, X, lane,  0, 0);
  branch_block<17, 64>(Wa_p, ba_p, Wa_u, ba_u, A, X, lane, 14, 1);
  branch_block<51, 32>(Wp_p, bp_p, Wp_u, bp_u, A, X, lane, 31, 2);
  branch_block< 7, 16>(Ws_p, bs_p, Ws_u, bs_u, A, X, lane, 82, 3);
  branch_block<10, 16>(Wt_p, bt_p, Wt_u, bt_u, A, X, lane, 89, 4);

  // ---------------- phase 3: QKV projections (lane = h*16+d) ----------------
  float qr[M][5], kr[M][5], vr[M][5];
  {
    const float bqv = bq[lane], bkv = bk[lane], bvv_ = bvv[lane];
    #pragma unroll
    for (int m = 0; m < M; ++m)
      #pragma unroll
      for (int s = 0; s < 5; ++s) { qr[m][s] = bqv; kr[m][s] = bkv; vr[m][s] = bvv_; }
    for (int e = 0; e < 64; ++e) {
      const float wq = Wq[e * 64 + lane];
      const float wk = Wk[e * 64 + lane];
      const float wv = Wvv[e * 64 + lane];
      #pragma unroll
      for (int m = 0; m < M; ++m)
        #pragma unroll
        for (int s = 0; s < 5; ++s) {
          const float xr = X[m * 320 + s * 64 + e];
          qr[m][s] += xr * wq; kr[m][s] += xr * wk; vr[m][s] += xr * wv;
        }
    }
  }

  // ---------------- phase 4: scores/softmax/o fully in registers ----------------
  float orr[M][5];
  #pragma unroll
  for (int m = 0; m < M; ++m) {
    #pragma unroll
    for (int qi = 0; qi < 5; ++qi) {
      float sc[5];
      #pragma unroll
      for (int ki = 0; ki < 5; ++ki) {
        float p = qr[m][qi] * kr[m][ki];
        p += __shfl_xor(p, 1); p += __shfl_xor(p, 2);
        p += __shfl_xor(p, 4); p += __shfl_xor(p, 8);
        sc[ki] = p * 0.25f;   // / sqrt(16)
      }
      float mx = fmaxf(fmaxf(fmaxf(sc[0], sc[1]), fmaxf(sc[2], sc[3])), sc[4]);
      float ssum = 0.f;
      #pragma unroll
      for (int ki = 0; ki < 5; ++ki) { sc[ki] = __expf(sc[ki] - mx); ssum += sc[ki]; }
      const float inv = 1.0f / ssum;
      float acc = 0.f;
      #pragma unroll
      for (int ki = 0; ki < 5; ++ki) acc += (sc[ki] * inv) * vr[m][ki];
      orr[m][qi] = acc;
    }
  }

  // ---------------- phase 5: stage o, output projection, residual+LN ----------------
  #pragma unroll
  for (int m = 0; m < M; ++m)
    #pragma unroll
    for (int s = 0; s < 5; ++s) A[m * 320 + s * 64 + lane] = orr[m][s];

  float att[M][5];
  {
    const float bov = bo[lane];
    #pragma unroll
    for (int m = 0; m < M; ++m)
      #pragma unroll
      for (int s = 0; s < 5; ++s) att[m][s] = bov;
    for (int hd = 0; hd < 64; ++hd) {
      const float w = Wo[hd * 64 + lane];
      #pragma unroll
      for (int m = 0; m < M; ++m)
        #pragma unroll
        for (int s = 0; s < 5; ++s) att[m][s] += A[m * 320 + s * 64 + hd] * w;
    }
  }
  {
    const float g = gamma[lane], be = beta[lane];
    #pragma unroll
    for (int m = 0; m < M; ++m)
      #pragma unroll
      for (int s = 0; s < 5; ++s) {
        const float hv = X[m * 320 + s * 64 + lane] + att[m][s];
        float s1 = hv, s2 = hv * hv;
        #pragma unroll
        for (int off = 32; off >= 1; off >>= 1) {
          s1 += __shfl_xor(s1, off);
          s2 += __shfl_xor(s2, off);
        }
        const float mean = s1 * 0.015625f;
        const float var  = s2 * 0.015625f - mean * mean;
        X[m * 320 + s * 64 + lane] = (hv - mean) * rsqrtf(var + 1e-3f) * g + be;
      }
  }

  // ---------------- phase 6: MLP layer 1: fused = relu(flat @ W1 + b1) ----------------
  {
    float acc[M][4];
    #pragma unroll
    for (int m = 0; m < M; ++m)
      #pragma unroll
      for (int rr = 0; rr < 4; ++rr) acc[m][rr] = b1[rr * 64 + lane];
    #pragma unroll 4
    for (int f = 0; f < 320; ++f) {
      const float w0 = W1[f * 256 +   0 + lane];
      const float w1 = W1[f * 256 +  64 + lane];
      const float w2 = W1[f * 256 + 128 + lane];
      const float w3 = W1[f * 256 + 192 + lane];
      #pragma unroll
      for (int m = 0; m < M; ++m) {
        const float xf = X[m * 320 + f];
        acc[m][0] += xf * w0; acc[m][1] += xf * w1;
        acc[m][2] += xf * w2; acc[m][3] += xf * w3;
      }
    }
    #pragma unroll
    for (int m = 0; m < M; ++m)
      #pragma unroll
      for (int rr = 0; rr < 4; ++rr)
        A[m * 256 + rr * 64 + lane] = fmaxf(acc[m][rr], 0.0f);
  }

  // ---------------- phase 7: MLP layer 2: context = relu(fused @ W2 + b2) ----------------
  {
    float a2[M][3];
    const int c2 = (lane < 32) ? (128 + lane) : 0;  // guarded 3rd column
    #pragma unroll
    for (int m = 0; m < M; ++m) {
      a2[m][0] = b2[lane];
      a2[m][1] = b2[64 + lane];
      a2[m][2] = (lane < 32) ? b2[128 + lane] : 0.f;
    }
    #pragma unroll 4
    for (int f = 0; f < 256; ++f) {
      const float w0 = W2[f * 160 + lane];
      const float w1 = W2[f * 160 + 64 + lane];
      const float w2v = W2[f * 160 + c2];
      #pragma unroll
      for (int m = 0; m < M; ++m) {
        const float xf = A[m * 256 + f];
        a2[m][0] += xf * w0; a2[m][1] += xf * w1; a2[m][2] += xf * w2v;
      }
    }
    #pragma unroll
    for (int m = 0; m < M; ++m) {
      float* op = out + (size_t)(rowBase + m) * 160;
      op[lane]      = fmaxf(a2[m][0], 0.0f);
      op[64 + lane] = fmaxf(a2[m][1], 0.0f);
      if (lane < 32) op[128 + lane] = fmaxf(a2[m][2], 0.0f);
    }
  }
}

extern "C" void kernel_launch(void* const* d_in, const int* in_sizes, int n_in,
                              void* d_out, int out_size, void* d_ws, size_t ws_size,
                              hipStream_t stream) {
  const float* visual  = (const float*)d_in[0];
  const float* audio   = (const float*)d_in[1];
  const float* pose    = (const float*)d_in[2];
  const float* spatial = (const float*)d_in[3];
  const float* timex   = (const float*)d_in[4];
  const float* Wv_p = (const float*)d_in[5];  const float* bv_p = (const float*)d_in[6];
  const float* Wa_p = (const float*)d_in[7];  const float* ba_p = (const float*)d_in[8];
  const float* Wp_p = (const float*)d_in[9];  const float* bp_p = (const float*)d_in[10];
  const float* Ws_p = (const float*)d_in[11]; const float* bs_p = (const float*)d_in[12];
  const float* Wt_p = (const float*)d_in[13]; const float* bt_p = (const float*)d_in[14];
  const float* Wv_u = (const float*)d_in[15]; const float* bv_u = (const float*)d_in[16];
  const float* Wa_u = (const float*)d_in[17]; const float* ba_u = (const float*)d_in[18];
  const float* Wp_u = (const float*)d_in[19]; const float* bp_u = (const float*)d_in[20];
  const float* Ws_u = (const float*)d_in[21]; const float* bs_u = (const float*)d_in[22];
  const float* Wt_u = (const float*)d_in[23]; const float* bt_u = (const float*)d_in[24];
  const float* Wq  = (const float*)d_in[25];  const float* bq  = (const float*)d_in[26];
  const float* Wk  = (const float*)d_in[27];  const float* bk  = (const float*)d_in[28];
  const float* Wvv = (const float*)d_in[29];  const float* bvv = (const float*)d_in[30];
  const float* Wo  = (const float*)d_in[31];  const float* bo  = (const float*)d_in[32];
  const float* gamma = (const float*)d_in[33]; const float* beta = (const float*)d_in[34];
  const float* W1 = (const float*)d_in[35];   const float* b1 = (const float*)d_in[36];
  const float* W2 = (const float*)d_in[37];   const float* b2 = (const float*)d_in[38];
  float* out = (float*)d_out;

  const int rows_per_block = WAVES * M;               // 16
  const int grid = NROWS / rows_per_block;            // 8192
  hipLaunchKernelGGL(ace_fused, dim3(grid), dim3(256), 0, stream,
                     visual, audio, pose, spatial, timex,
                     Wv_p, bv_p, Wa_p, ba_p, Wp_p, bp_p, Ws_p, bs_p, Wt_p, bt_p,
                     Wv_u, bv_u, Wa_u, ba_u, Wp_u, bp_u, Ws_u, bs_u, Wt_u, bt_u,
                     Wq, bq, Wk, bk, Wvv, bvv, Wo, bo, gamma, beta,
                     W1, b1, W2, b2, out);
}